// Round 6
// baseline (54.572 us; speedup 1.0000x reference)
//
#include <hip/hip_runtime.h>

#define BATCH  64
#define TLEN   2048
#define DDIM   256
#define ADIM   128
#define TM     64          // t-rows per tile
#define NTILES 8           // tiles per block
#define EPSC   1e-7f

typedef __bf16 bf16x8 __attribute__((ext_vector_type(8)));
typedef float  f32x4  __attribute__((ext_vector_type(4)));

// DPP-based add of a lane-permuted copy (VALU pipe, not LDS)
template <int CTRL>
__device__ __forceinline__ float dpp_add(float v) {
    int vi = __builtin_bit_cast(int, v);
    int sw = __builtin_amdgcn_update_dpp(vi, vi, CTRL, 0xF, 0xF, false);
    return v + __builtin_bit_cast(float, sw);
}

// async global->LDS DMA, 16B per lane; LDS dest = uniform base + lane*16
__device__ __forceinline__ void gload_lds16(const void* g, void* l) {
    __builtin_amdgcn_global_load_lds(
        (const __attribute__((address_space(1))) void*)g,
        (__attribute__((address_space(3))) void*)l, 16, 0, 0);
}

// ws layout:
//   [0,      65536)  : Wf  bf16[32768]  (B-fragment-ordered W)
//   [65536, 131072)  : N   f32[16384]   (unnormalized numerator, per b,d)
//   [131072,131328)  : s   f32[64]      (unnormalized denominator, per b)

__global__ __launch_bounds__(256) void prep_kernel(const float* __restrict__ W,
                                                   __bf16* __restrict__ Wf,
                                                   float* __restrict__ N,
                                                   float* __restrict__ s) {
    int idx = blockIdx.x * 256 + threadIdx.x;   // [0, 32768)
    int j  = idx & 7;
    int l  = (idx >> 3) & 63;
    int nt = (idx >> 9) & 7;
    int kt = idx >> 12;
    int k = kt * 32 + (l >> 4) * 8 + j;         // K index into D
    int n = nt * 16 + (l & 15);                 // N index into A
    Wf[idx] = (__bf16)W[k * ADIM + n];
    if (idx < BATCH * DDIM) N[idx] = 0.0f;
    if (idx >= BATCH * DDIM && idx < BATCH * DDIM + BATCH) s[idx - BATCH * DDIM] = 0.0f;
}

__global__ __launch_bounds__(256) void attn_main(const float* __restrict__ x,
                                                 const float* __restrict__ bias,
                                                 const float* __restrict__ u,
                                                 const __bf16* __restrict__ Wf,
                                                 float* __restrict__ N,
                                                 float* __restrict__ s) {
    __shared__ float xs[2][TM * DDIM];    // 2 x 64 KB f32, source-swizzled rows
    __shared__ float wpart[4][TM];        // per-wave 32-col row partials
    __shared__ float wlds[TM];            // exp(z) per row of current tile

    const int b    = blockIdx.x >> 2;              // 4 blocks per batch
    const int t00  = (blockIdx.x & 3) * (NTILES * TM);
    const int tid  = threadIdx.x;
    const int wave = tid >> 6;
    const int lane = tid & 63;
    const int lm   = lane & 15;                    // col index within 16x16 C tile
    const int lk   = lane >> 4;                    // k-block / row-quad index

    // wave w owns A-columns [w*32, w*32+32)
    float bias_r[2], u_r[2];
#pragma unroll
    for (int ntl = 0; ntl < 2; ++ntl) {
        bias_r[ntl] = bias[wave * 32 + ntl * 16 + lm];
        u_r[ntl]    = u[wave * 32 + ntl * 16 + lm];
    }

    // hoist Wf fragments for this wave's 2 n-tiles across all kt (32 VGPRs)
    bf16x8 wfreg[8][2];
#pragma unroll
    for (int kt = 0; kt < 8; ++kt)
#pragma unroll
        for (int ntl = 0; ntl < 2; ++ntl)
            wfreg[kt][ntl] = *(const bf16x8*)(Wf + ((size_t)((kt * 8 + wave * 2 + ntl) * 64 + lane)) * 8);

    float accd = 0.f;   // pooling accumulator: this thread owns column d = tid
    float sreg = 0.f;   // denominator partial (wave 0 lanes)

    const float* xblk = x + (size_t)(b * TLEN + t00) * DDIM;

    // ---- prologue: DMA tile 0 into xs[0] ----
#pragma unroll
    for (int i = 0; i < 16; ++i) {
        const int r = wave * 16 + i;
        const unsigned sw = ((unsigned)(lane * 16)) ^ (unsigned)((r & 7) << 4);
        gload_lds16((const char*)(xblk + (size_t)r * DDIM) + sw,
                    (char*)&xs[0][r * DDIM]);
    }
    __syncthreads();   // drains vmcnt(0): tile 0 resident

    for (int it = 0; it < NTILES; ++it) {
        const float* buf = xs[it & 1];

        // ---- issue DMA for next tile (stays in flight across raw barriers) ----
        if (it + 1 < NTILES) {
            const float* nb = xblk + (size_t)(it + 1) * TM * DDIM;
            float* dst = xs[(it + 1) & 1];
#pragma unroll
            for (int i = 0; i < 16; ++i) {
                const int r = wave * 16 + i;
                const unsigned sw = ((unsigned)(lane * 16)) ^ (unsigned)((r & 7) << 4);
                gload_lds16((const char*)(nb + (size_t)r * DDIM) + sw,
                            (char*)(dst + r * DDIM));
            }
        }

        // ---- GEMM: 64 rows x 32 cols per wave; f32 frags from LDS, cvt to bf16 ----
        f32x4 acc[4][2];
#pragma unroll
        for (int m = 0; m < 4; ++m)
#pragma unroll
            for (int ntl = 0; ntl < 2; ++ntl) acc[m][ntl] = (f32x4){0.f, 0.f, 0.f, 0.f};

#pragma unroll
        for (int kt = 0; kt < 8; ++kt) {
#pragma unroll
            for (int m = 0; m < 4; ++m) {
                const int r = m * 16 + lm;
                const unsigned msk  = (unsigned)((r & 7) << 4);
                const unsigned base = (unsigned)(kt * 128 + lk * 32);
                const char* rowp = (const char*)(buf + r * DDIM);
                f32x4 lo = *(const f32x4*)(rowp + (base ^ msk));
                f32x4 hi = *(const f32x4*)(rowp + ((base + 16u) ^ msk));
                bf16x8 a;
#pragma unroll
                for (int i = 0; i < 4; ++i) { a[i] = (__bf16)lo[i]; a[4 + i] = (__bf16)hi[i]; }
                acc[m][0] = __builtin_amdgcn_mfma_f32_16x16x32_bf16(a, wfreg[kt][0], acc[m][0], 0, 0, 0);
                acc[m][1] = __builtin_amdgcn_mfma_f32_16x16x32_bf16(a, wfreg[kt][1], acc[m][1], 0, 0, 0);
            }
        }

        // ---- logits -> per-wave 32-col partial row sums (DPP, VALU pipe) ----
#pragma unroll
        for (int m = 0; m < 4; ++m) {
#pragma unroll
            for (int reg = 0; reg < 4; ++reg) {
                float p = 0.f;
#pragma unroll
                for (int ntl = 0; ntl < 2; ++ntl) {
                    float lg = acc[m][ntl][reg] + bias_r[ntl];
                    float e  = __expf(2.0f * lg);
                    float th = 1.0f - 2.0f * __builtin_amdgcn_rcpf(e + 1.0f);  // tanh, inf-safe
                    p += th * u_r[ntl];
                }
                p = dpp_add<0xB1>(p);   // xor 1
                p = dpp_add<0x4E>(p);   // xor 2
                p = dpp_add<0x141>(p);  // row_half_mirror
                p = dpp_add<0x140>(p);  // row_mirror -> full 16-lane sum
                if (lm == 0) wpart[wave][m * 16 + lk * 4 + reg] = p;
            }
        }
        // raw barrier: order LDS only, keep DMA (vmcnt) in flight
        asm volatile("s_waitcnt lgkmcnt(0)" ::: "memory");
        __builtin_amdgcn_s_barrier();

        // ---- combine wave partials, exp; accumulate denominator in regs ----
        if (tid < TM) {   // wave 0
            float z  = wpart[0][tid] + wpart[1][tid] + wpart[2][tid] + wpart[3][tid];
            float wv = __expf(z);
            wlds[tid] = wv;
            sreg += wv;
        }
        asm volatile("s_waitcnt lgkmcnt(0)" ::: "memory");
        __builtin_amdgcn_s_barrier();

        // ---- pooling: thread owns column d = tid; f32 reads, readlane weights ----
        float wr = wlds[lane];   // lane t holds exp-weight of row t
#pragma unroll
        for (int s8 = 0; s8 < 8; ++s8) {
            const unsigned cb = ((unsigned)(tid * 4)) ^ (unsigned)(s8 << 4);
#pragma unroll
            for (int tt = 0; tt < 8; ++tt) {
                const int t = tt * 8 + s8;   // t & 7 == s8
                float xv = *(const float*)((const char*)(buf + t * DDIM) + cb);
                float wt = __builtin_bit_cast(float,
                            __builtin_amdgcn_readlane(__builtin_bit_cast(int, wr), t));
                accd += xv * wt;
            }
        }
        // full barrier: drains vmcnt -> next tile resident; orders LDS reuse
        __syncthreads();
    }

    // ---- epilogue: denominator ----
    if (tid < TM) {
        float ss = sreg;
#pragma unroll
        for (int off = 1; off < 64; off <<= 1) ss += __shfl_xor(ss, off);
        if (tid == 0) atomicAdd(&s[b], ss);
    }
    // ---- epilogue: numerator (one column per thread) ----
    atomicAdd(&N[b * DDIM + tid], accd);
}

__global__ __launch_bounds__(256) void finalize_kernel(const float* __restrict__ N,
                                                       const float* __restrict__ s,
                                                       float* __restrict__ out) {
    int idx = blockIdx.x * 256 + threadIdx.x;   // [0, 16384)
    out[idx] = N[idx] / (s[idx >> 8] + EPSC);
}

extern "C" void kernel_launch(void* const* d_in, const int* in_sizes, int n_in,
                              void* d_out, int out_size, void* d_ws, size_t ws_size,
                              hipStream_t stream) {
    const float* x    = (const float*)d_in[0];
    const float* W    = (const float*)d_in[1];
    const float* bias = (const float*)d_in[2];
    const float* u    = (const float*)d_in[3];
    float* out = (float*)d_out;

    char* ws = (char*)d_ws;
    __bf16* Wf = (__bf16*)ws;
    float*  N  = (float*)(ws + 65536);
    float*  s  = (float*)(ws + 131072);

    prep_kernel<<<128, 256, 0, stream>>>(W, Wf, N, s);
    attn_main<<<BATCH * TLEN / (NTILES * TM), 256, 0, stream>>>(x, bias, u, Wf, N, s);
    finalize_kernel<<<(BATCH * DDIM) / 256, 256, 0, stream>>>(N, s, out);
}

// Round 7
// 41.866 us; speedup vs baseline: 1.3035x; 1.3035x over previous
//
#include <hip/hip_runtime.h>

#define BATCH 64
#define TLEN  2048
#define DDIM  256
#define ADIM  128
#define TM    64          // t-rows per tile
#define TILES 4           // tiles per block
#define EPSC  1e-7f

typedef __bf16 bf16x8 __attribute__((ext_vector_type(8)));
typedef float  f32x4  __attribute__((ext_vector_type(4)));

// DPP-based add of a lane-permuted copy (VALU pipe, not LDS)
template <int CTRL>
__device__ __forceinline__ float dpp_add(float v) {
    int vi = __builtin_bit_cast(int, v);
    int sw = __builtin_amdgcn_update_dpp(vi, vi, CTRL, 0xF, 0xF, false);
    return v + __builtin_bit_cast(float, sw);
}

// raw workgroup barrier: orders LDS only, leaves global loads (vmcnt) in flight
__device__ __forceinline__ void bar_lds() {
    asm volatile("s_waitcnt lgkmcnt(0)" ::: "memory");
    __builtin_amdgcn_s_barrier();
}

// ws layout:
//   [0,      65536)  : Wf  bf16[32768]  (B-fragment-ordered W)
//   [65536, 131072)  : N   f32[16384]   (unnormalized numerator, per b,d)
//   [131072,131328)  : s   f32[64]      (unnormalized denominator, per b)

__global__ __launch_bounds__(256) void prep_kernel(const float* __restrict__ W,
                                                   __bf16* __restrict__ Wf,
                                                   float* __restrict__ N,
                                                   float* __restrict__ s) {
    int idx = blockIdx.x * 256 + threadIdx.x;   // [0, 32768)
    int j  = idx & 7;
    int l  = (idx >> 3) & 63;
    int nt = (idx >> 9) & 7;
    int kt = idx >> 12;
    int k = kt * 32 + (l >> 4) * 8 + j;         // K index into D
    int n = nt * 16 + (l & 15);                 // N index into A
    Wf[idx] = (__bf16)W[k * ADIM + n];
    if (idx < BATCH * DDIM) N[idx] = 0.0f;
    if (idx >= BATCH * DDIM && idx < BATCH * DDIM + BATCH) s[idx - BATCH * DDIM] = 0.0f;
}

__global__ __launch_bounds__(256, 2) void attn_main(const float* __restrict__ x,
                                                    const float* __restrict__ bias,
                                                    const float* __restrict__ u,
                                                    const __bf16* __restrict__ Wf,
                                                    float* __restrict__ N,
                                                    float* __restrict__ s) {
    __shared__ char  xs[2][TM * DDIM * 2];   // 2 x 32 KB, XOR-swizzled 16B blocks
    __shared__ float wpart[4][TM];           // per-wave 32-col row partials
    __shared__ float wlds[TM];               // exp(z) per row of current tile
    __shared__ float fpart[4][32][8];        // pooling partials (4 KB)

    const int b    = blockIdx.x >> 3;            // 8 blocks per batch
    const int t00  = (blockIdx.x & 7) * (TILES * TM);
    const int tid  = threadIdx.x;
    const int wave = tid >> 6;
    const int lane = tid & 63;
    const int lm   = lane & 15;                  // col index within 16x16 C tile
    const int lk   = lane >> 4;                  // k-block / row-quad index
    const int row  = wave * 16 + lm;             // local row this thread stages

    // wave w owns A-columns [w*32, w*32+32)
    float bias_r[2], u_r[2];
#pragma unroll
    for (int ntl = 0; ntl < 2; ++ntl) {
        bias_r[ntl] = bias[wave * 32 + ntl * 16 + lm];
        u_r[ntl]    = u[wave * 32 + ntl * 16 + lm];
    }

    // hoist Wf fragments for this wave's 2 n-tiles across all kt (64 VGPRs)
    bf16x8 wfreg[8][2];
#pragma unroll
    for (int kt = 0; kt < 8; ++kt)
#pragma unroll
        for (int ntl = 0; ntl < 2; ++ntl)
            wfreg[kt][ntl] = *(const bf16x8*)(Wf + ((size_t)((kt * 8 + wave * 2 + ntl) * 64 + lane)) * 8);

    float vacc[8] = {0.f, 0.f, 0.f, 0.f, 0.f, 0.f, 0.f, 0.f};
    float sreg = 0.f;
    const int dgrp = tid & 31;     // pooling: d = dgrp*8 + j
    const int tgrp = tid >> 5;     // pooling: t = tgrp*8 + i

    const float* xbase = x + ((size_t)(b * TLEN + t00 + row)) * DDIM;

    // ---- prologue: load tile 0 into registers ----
    f32x4 fa[8], fb[8];
#pragma unroll
    for (int kt = 0; kt < 8; ++kt) {
        fa[kt] = *(const f32x4*)(xbase + kt * 32 + lk * 8);
        fb[kt] = *(const f32x4*)(xbase + kt * 32 + lk * 8 + 4);
    }

    for (int it = 0; it < TILES; ++it) {
        char* buf = xs[it & 1];

        // ---- cvt + stash current tile (consumes fa/fb) ----
#pragma unroll
        for (int kt = 0; kt < 8; ++kt) {
            bf16x8 a;
#pragma unroll
            for (int i = 0; i < 4; ++i) { a[i] = (__bf16)fa[kt][i]; a[4 + i] = (__bf16)fb[kt][i]; }
            *(bf16x8*)(buf + ((row * 512 + (kt * 32 + lk * 8) * 2) ^ ((row & 7) << 4))) = a;
        }

        // ---- issue next tile's loads BEFORE the barrier: in flight across the
        //      whole tile (raw barriers below never drain vmcnt) ----
        if (it + 1 < TILES) {
            const float* xn = xbase + (size_t)(it + 1) * TM * DDIM;
#pragma unroll
            for (int kt = 0; kt < 8; ++kt) {
                fa[kt] = *(const f32x4*)(xn + kt * 32 + lk * 8);
                fb[kt] = *(const f32x4*)(xn + kt * 32 + lk * 8 + 4);
            }
        }
        bar_lds();   // stash visible to all waves; prefetch NOT drained

        // ---- GEMM: 64 rows x 32 cols per wave, A-frags from LDS, W from regs ----
        f32x4 acc[4][2];
#pragma unroll
        for (int m = 0; m < 4; ++m)
#pragma unroll
            for (int ntl = 0; ntl < 2; ++ntl) acc[m][ntl] = (f32x4){0.f, 0.f, 0.f, 0.f};

#pragma unroll
        for (int kt = 0; kt < 8; ++kt) {
#pragma unroll
            for (int m = 0; m < 4; ++m) {
                const int r = m * 16 + lm;
                bf16x8 afrag = *(const bf16x8*)(buf + ((r * 512 + (kt * 32 + lk * 8) * 2) ^ ((r & 7) << 4)));
                acc[m][0] = __builtin_amdgcn_mfma_f32_16x16x32_bf16(afrag, wfreg[kt][0], acc[m][0], 0, 0, 0);
                acc[m][1] = __builtin_amdgcn_mfma_f32_16x16x32_bf16(afrag, wfreg[kt][1], acc[m][1], 0, 0, 0);
            }
        }

        // ---- logits -> per-wave 32-col partial row sums (DPP, VALU pipe) ----
#pragma unroll
        for (int m = 0; m < 4; ++m) {
#pragma unroll
            for (int reg = 0; reg < 4; ++reg) {
                float p = 0.f;
#pragma unroll
                for (int ntl = 0; ntl < 2; ++ntl) {
                    float lg = acc[m][ntl][reg] + bias_r[ntl];
                    float e  = __expf(2.0f * lg);
                    float th = 1.0f - 2.0f * __builtin_amdgcn_rcpf(e + 1.0f);  // tanh, inf-safe
                    p += th * u_r[ntl];
                }
                p = dpp_add<0xB1>(p);   // xor 1
                p = dpp_add<0x4E>(p);   // xor 2
                p = dpp_add<0x141>(p);  // row_half_mirror
                p = dpp_add<0x140>(p);  // row_mirror -> full 16-lane sum
                if (lm == 0) wpart[wave][m * 16 + lk * 4 + reg] = p;
            }
        }
        bar_lds();

        // ---- combine wave partials, exp; accumulate denominator in regs ----
        if (tid < TM) {   // wave 0
            float z  = wpart[0][tid] + wpart[1][tid] + wpart[2][tid] + wpart[3][tid];
            float wv = __expf(z);
            wlds[tid] = wv;
            sreg += wv;
        }
        bar_lds();

        // ---- pooling: accumulate into persistent vacc ----
#pragma unroll
        for (int i = 0; i < 8; ++i) {
            const int t = tgrp * 8 + i;
            bf16x8 xv = *(const bf16x8*)(buf + ((t * 512 + dgrp * 16) ^ ((t & 7) << 4)));
            float wt = wlds[t];
#pragma unroll
            for (int j = 0; j < 8; ++j) vacc[j] += (float)xv[j] * wt;
        }
        // no barrier here: next stash writes the OTHER buffer; wpart/wlds rewrites
        // are separated from this tile's reads by the next iteration's barriers.
    }

    // ---- epilogue: denominator ----
    if (tid < TM) {
        float ss = sreg;
#pragma unroll
        for (int off = 1; off < 64; off <<= 1) ss += __shfl_xor(ss, off);
        if (tid == 0) atomicAdd(&s[b], ss);
    }

    // ---- epilogue: numerator ----
#pragma unroll
    for (int j = 0; j < 8; ++j) vacc[j] += __shfl_xor(vacc[j], 32);
    if (lane < 32) {
        *(f32x4*)&fpart[wave][dgrp][0] = (f32x4){vacc[0], vacc[1], vacc[2], vacc[3]};
        *(f32x4*)&fpart[wave][dgrp][4] = (f32x4){vacc[4], vacc[5], vacc[6], vacc[7]};
    }
    __syncthreads();
    float r = fpart[0][tid >> 3][tid & 7] + fpart[1][tid >> 3][tid & 7]
            + fpart[2][tid >> 3][tid & 7] + fpart[3][tid >> 3][tid & 7];
    atomicAdd(&N[b * DDIM + tid], r);
}

__global__ __launch_bounds__(256) void finalize_kernel(const float* __restrict__ N,
                                                       const float* __restrict__ s,
                                                       float* __restrict__ out) {
    int idx = blockIdx.x * 256 + threadIdx.x;   // [0, 16384)
    out[idx] = N[idx] / (s[idx >> 8] + EPSC);
}

extern "C" void kernel_launch(void* const* d_in, const int* in_sizes, int n_in,
                              void* d_out, int out_size, void* d_ws, size_t ws_size,
                              hipStream_t stream) {
    const float* x    = (const float*)d_in[0];
    const float* W    = (const float*)d_in[1];
    const float* bias = (const float*)d_in[2];
    const float* u    = (const float*)d_in[3];
    float* out = (float*)d_out;

    char* ws = (char*)d_ws;
    __bf16* Wf = (__bf16*)ws;
    float*  N  = (float*)(ws + 65536);
    float*  s  = (float*)(ws + 131072);

    prep_kernel<<<128, 256, 0, stream>>>(W, Wf, N, s);
    attn_main<<<BATCH * TLEN / (TILES * TM), 256, 0, stream>>>(x, bias, u, Wf, N, s);
    finalize_kernel<<<(BATCH * DDIM) / 256, 256, 0, stream>>>(N, s, out);
}